// Round 1
// baseline (274.059 us; speedup 1.0000x reference)
//
#include <hip/hip_runtime.h>

#define N_    8
#define C_    256
#define H_    100
#define W_    152
#define HW_   (H_*W_)          // 15200
#define NT_   20
#define TEMP_ 0.5f
#define LN_EPS_ 1e-5f
#define PB_   ((HW_+255)/256)  // 60 pixel-blocks of 256
#define CC_   4                // channel chunks in pass1
#define CL_   (C_/CC_)         // 64 channels per chunk

__device__ __forceinline__ float wred_sum(float v){
#pragma unroll
  for(int o=32;o;o>>=1) v += __shfl_xor(v,o,64);
  return v;
}
__device__ __forceinline__ float wred_max(float v){
#pragma unroll
  for(int o=32;o;o>>=1) v = fmaxf(v,__shfl_xor(v,o,64));
  return v;
}
// returns block-wide sum to ALL threads; sm must hold >=4 floats
__device__ float block_sum(float v, float* sm){
  v = wred_sum(v);
  __syncthreads();
  if((threadIdx.x&63)==0) sm[threadIdx.x>>6]=v;
  __syncthreads();
  float r=0.f; int nw = blockDim.x>>6;
#pragma unroll
  for(int i=0;i<4;i++) if(i<nw) r+=sm[i];
  return r;
}
__device__ float block_max(float v, float* sm){
  v = wred_max(v);
  __syncthreads();
  if((threadIdx.x&63)==0) sm[threadIdx.x>>6]=v;
  __syncthreads();
  float r=-3.4e38f; int nw = blockDim.x>>6;
#pragma unroll
  for(int i=0;i<4;i++) if(i<nw) r=fmaxf(r,sm[i]);
  return r;
}

// acc layout: 0 fg, 1 bg, 2 total_d2, 3 maskS, 4 maskC, 5 rela, 6..13 bgcnt[n]
__global__ void k_masks(const float* __restrict__ gt, const int* __restrict__ imh,
                        const int* __restrict__ imw,
                        float* __restrict__ mask_fg, float* __restrict__ acc){
  __shared__ float sm[4];
  int b = blockIdx.x;
  int n = b / PB_;
  int pp = (b % PB_)*256 + threadIdx.x;
  float sw = (float)W_ / (float)imw[0];
  float sh = (float)H_ / (float)imh[0];
  float fg = 0.f;
  bool valid = pp < HW_;
  if (valid){
    float hh = (float)(pp / W_);
    float ww = (float)(pp % W_);
#pragma unroll
    for(int t=0;t<NT_;t++){
      const float* bx = gt + ((size_t)(n*NT_)+t)*4;
      float wmin = floorf(bx[0]*sw);
      float hmin = floorf(bx[1]*sh);
      float wmax = ceilf (bx[2]*sw);
      float hmax = ceilf (bx[3]*sh);
      float area = 1.f/((hmax+1.f-hmin)*(wmax+1.f-wmin));
      bool in = (hh>=hmin)&&(hh<=hmax)&&(ww>=wmin)&&(ww<=wmax);
      fg = fmaxf(fg, in?area:0.f);
    }
    mask_fg[n*HW_+pp] = fg;
  }
  float bgf = (valid && fg<=0.f) ? 1.f : 0.f;
  float s = block_sum(bgf, sm);
  if(threadIdx.x==0) atomicAdd(&acc[6+n], s);
}

__global__ void __launch_bounds__(256) k_pass1(
    const float* __restrict__ S, const float* __restrict__ T,
    const float* __restrict__ ws_w, const float* __restrict__ wt_w,
    const float* __restrict__ mask_fg,
    float* __restrict__ fea_s, float* __restrict__ fea_t,
    float* __restrict__ cmp_s, float* __restrict__ cmp_t,
    float* __restrict__ ch_s, float* __restrict__ ch_t,
    float* __restrict__ sum_d, float* __restrict__ acc){
  __shared__ float part[3][4][CL_];
  __shared__ float lw_s[CL_], lw_t[CL_];
  __shared__ float sm[4];
  int b = blockIdx.x;
  int cc = b % CC_;
  int pb = (b/CC_) % PB_;
  int n  = b/(CC_*PB_);
  int c0 = cc*CL_;
  int tid = threadIdx.x;
  if (tid < CL_){ lw_s[tid] = ws_w[c0+tid]; lw_t[tid] = wt_w[c0+tid]; }
  __syncthreads();
  int pp = pb*256 + tid;
  bool valid = pp < HW_;
  int wv = tid>>6, ln = tid&63;
  const float* Sp = S + (size_t)(n*C_+c0)*HW_ + pp;
  const float* Tp = T + (size_t)(n*C_+c0)*HW_ + pp;
  float facc_s=0.f, facc_t=0.f, cacc_s=0.f, cacc_t=0.f, d2acc=0.f;
  for(int ci=0; ci<CL_; ci++){
    float s = valid ? Sp[(size_t)ci*HW_] : 0.f;
    float t = valid ? Tp[(size_t)ci*HW_] : 0.f;
    float as = fabsf(s), at = fabsf(t);
    float d = s - t;
    facc_s += as; facc_t += at;
    cacc_s += lw_s[ci]*s; cacc_t += lw_t[ci]*t;
    d2acc += d*d;
    float r0 = wred_sum(as);
    float r1 = wred_sum(at);
    float r2 = wred_sum(d);
    if(ln==0){ part[0][wv][ci]=r0; part[1][wv][ci]=r1; part[2][wv][ci]=r2; }
  }
  if(valid){
    atomicAdd(&fea_s[n*HW_+pp], facc_s);
    atomicAdd(&fea_t[n*HW_+pp], facc_t);
    atomicAdd(&cmp_s[n*HW_+pp], cacc_s);
    atomicAdd(&cmp_t[n*HW_+pp], cacc_t);
  }
  float mfg = valid ? mask_fg[n*HW_+pp] : 0.f;
  float bgc = acc[6+n];
  float mbg = 0.f;
  if(valid && mfg<=0.f) mbg = (bgc>0.f)?(1.f/bgc):1.f;
  float s1 = block_sum(mfg*mfg*d2acc, sm);
  if(tid==0) atomicAdd(&acc[0], s1);
  float s2 = block_sum(mbg*mbg*d2acc, sm);
  if(tid==0) atomicAdd(&acc[1], s2);
  float s3 = block_sum(d2acc, sm);
  if(tid==0) atomicAdd(&acc[2], s3);
  __syncthreads();
  if(tid < CL_){
    float v0 = part[0][0][tid]+part[0][1][tid]+part[0][2][tid]+part[0][3][tid];
    float v1 = part[1][0][tid]+part[1][1][tid]+part[1][2][tid]+part[1][3][tid];
    float v2 = part[2][0][tid]+part[2][1][tid]+part[2][2][tid]+part[2][3][tid];
    atomicAdd(&ch_s[n*C_+c0+tid], v0);
    atomicAdd(&ch_t[n*C_+c0+tid], v1);
    atomicAdd(&sum_d[n*C_+c0+tid], v2);
  }
}

__global__ void k_spatial(const float* __restrict__ fea_s, const float* __restrict__ fea_t,
                          float* __restrict__ cmp_s, float* __restrict__ cmp_t,
                          float* __restrict__ acc){
  __shared__ float sm[4];
  int n = blockIdx.x, tid = threadIdx.x;
  const float* fs = fea_s + n*HW_;
  const float* ft = fea_t + n*HW_;
  float* cs = cmp_s + n*HW_;
  float* ct = cmp_t + n*HW_;
  const float invf = 1.f/((float)C_*TEMP_);
  float m1=-3.4e38f,m2=-3.4e38f,m3=-3.4e38f,m4=-3.4e38f;
  for(int p=tid;p<HW_;p+=256){
    m1=fmaxf(m1,fs[p]); m2=fmaxf(m2,ft[p]);
    m3=fmaxf(m3,cs[p]); m4=fmaxf(m4,ct[p]);
  }
  m1=block_max(m1,sm); m2=block_max(m2,sm);
  m3=block_max(m3,sm); m4=block_max(m4,sm);
  float z1=0,z2=0,z3=0,z4=0;
  for(int p=tid;p<HW_;p+=256){
    z1+=expf((fs[p]-m1)*invf); z2+=expf((ft[p]-m2)*invf);
    z3+=expf(cs[p]-m3);        z4+=expf(ct[p]-m4);
  }
  z1=block_sum(z1,sm); z2=block_sum(z2,sm);
  z3=block_sum(z3,sm); z4=block_sum(z4,sm);
  float i1=(float)HW_/z1, i2=(float)HW_/z2, i3=1.f/z3, i4=1.f/z4;
  float dacc=0.f;
  for(int p=tid;p<HW_;p+=256){
    float Ss = expf((fs[p]-m1)*invf)*i1;
    float St = expf((ft[p]-m2)*invf)*i2;
    dacc += fabsf(Ss-St);
    float ps = expf(cs[p]-m3)*i3;
    float pt = expf(ct[p]-m4)*i4;
    cs[p]=ps; ct[p]=pt;
  }
  dacc = block_sum(dacc,sm);
  if(tid==0) atomicAdd(&acc[3], dacc);
}

__global__ void k_channel(const float* __restrict__ ch_s, const float* __restrict__ ch_t,
                          float* __restrict__ acc){
  __shared__ float sm[4];
  int n=blockIdx.x, c=threadIdx.x;
  const float invc = 1.f/((float)HW_*TEMP_);
  float vs = ch_s[n*C_+c]*invc;
  float vt = ch_t[n*C_+c]*invc;
  float ms = block_max(vs,sm);
  float mt = block_max(vt,sm);
  float es = expf(vs-ms), et = expf(vt-mt);
  float zs = block_sum(es,sm), zt = block_sum(et,sm);
  float Cs = (float)C_*es/zs, Ct = (float)C_*et/zt;
  float d = block_sum(fabsf(Cs-Ct), sm);
  if(c==0) atomicAdd(&acc[4], d);
}

__global__ void __launch_bounds__(256) k_pass2(
    const float* __restrict__ S, const float* __restrict__ T,
    const float* __restrict__ cmp_s, const float* __restrict__ cmp_t,
    float* __restrict__ ctx_s, float* __restrict__ ctx_t){
  __shared__ float sm[4];
  int b=blockIdx.x;
  int n=b>>8, c=b&255;
  const float* Sp = S + (size_t)(n*C_+c)*HW_;
  const float* Tp = T + (size_t)(n*C_+c)*HW_;
  const float* ps = cmp_s + n*HW_;
  const float* pt = cmp_t + n*HW_;
  float as=0.f, at=0.f;
  for(int p=threadIdx.x;p<HW_;p+=256){
    as += Sp[p]*ps[p];
    at += Tp[p]*pt[p];
  }
  as = block_sum(as,sm);
  at = block_sum(at,sm);
  if(threadIdx.x==0){ ctx_s[n*C_+c]=as; ctx_t[n*C_+c]=at; }
}

__global__ void k_cadd(const float* __restrict__ ctx_s, const float* __restrict__ ctx_t,
    const float* __restrict__ sw1, const float* __restrict__ sb1,
    const float* __restrict__ slnw, const float* __restrict__ slnb,
    const float* __restrict__ sw2, const float* __restrict__ sb2,
    const float* __restrict__ tw1, const float* __restrict__ tb1,
    const float* __restrict__ tlnw, const float* __restrict__ tlnb,
    const float* __restrict__ tw2, const float* __restrict__ tb2,
    const float* __restrict__ sum_d, float* __restrict__ acc){
  __shared__ float sm[4];
  __shared__ float lcs[C_], lct[C_], ly[C_], lh[C_];
  int n=blockIdx.x, tid=threadIdx.x;
  lcs[tid]=ctx_s[n*C_+tid]; lct[tid]=ctx_t[n*C_+tid];
  __syncthreads();
  {
    int half = tid>>7, k = tid&127;
    const float* w1  = half? tw1 : sw1;
    const float* b1  = half? tb1 : sb1;
    const float* src = half? lct : lcs;
    float a = b1[k];
    for(int c=0;c<C_;c++) a += src[c]*w1[k*C_+c];
    ly[tid]=a;
  }
  __syncthreads();
  {
    int half = tid>>7, k = tid&127;
    int base = half<<7;
    float mu=0.f;
    for(int i=0;i<128;i++) mu += ly[base+i];
    mu *= (1.f/128.f);
    float var=0.f;
    for(int i=0;i<128;i++){ float d=ly[base+i]-mu; var += d*d; }
    var *= (1.f/128.f);
    const float* lnw = half? tlnw : slnw;
    const float* lnb = half? tlnb : slnb;
    float yv = (ly[tid]-mu)/sqrtf(var+LN_EPS_)*lnw[k]+lnb[k];
    lh[tid] = fmaxf(yv, 0.f);
  }
  __syncthreads();
  {
    int c = tid;
    float os = sb2[c], ot = tb2[c];
    for(int k=0;k<128;k++){ os += lh[k]*sw2[c*128+k]; ot += lh[128+k]*tw2[c*128+k]; }
    float e = os - ot;
    float part = 2.f*e*sum_d[n*C_+c] + (float)HW_*e*e;
    float s = block_sum(part, sm);
    if(tid==0) atomicAdd(&acc[5], s);
  }
}

__global__ void k_final(const float* __restrict__ acc, float* __restrict__ out){
  if(threadIdx.x==0 && blockIdx.x==0){
    float fg=acc[0], bg=acc[1], d2=acc[2], mS=acc[3], mC=acc[4], rl=acc[5];
    const float invN = 1.f/(float)N_;
    out[0] = 0.001f*fg*invN + 0.0005f*bg*invN
           + 0.001f*(mC+mS)*invN + 5e-6f*(d2+rl)*invN;
  }
}

extern "C" void kernel_launch(void* const* d_in, const int* in_sizes, int n_in,
                              void* d_out, int out_size, void* d_ws, size_t ws_size,
                              hipStream_t stream){
  (void)in_sizes; (void)n_in; (void)out_size; (void)ws_size;
  const float* S     = (const float*)d_in[0];
  const float* T     = (const float*)d_in[1];
  const float* gt    = (const float*)d_in[2];
  const float* cms_w = (const float*)d_in[3];
  const float* cmt_w = (const float*)d_in[5];
  const float* cas_w1=(const float*)d_in[7],  *cas_b1=(const float*)d_in[8];
  const float* cas_lnw=(const float*)d_in[9], *cas_lnb=(const float*)d_in[10];
  const float* cas_w2=(const float*)d_in[11], *cas_b2=(const float*)d_in[12];
  const float* cat_w1=(const float*)d_in[13], *cat_b1=(const float*)d_in[14];
  const float* cat_lnw=(const float*)d_in[15],*cat_lnb=(const float*)d_in[16];
  const float* cat_w2=(const float*)d_in[17], *cat_b2=(const float*)d_in[18];
  const int* imh=(const int*)d_in[19];
  const int* imw=(const int*)d_in[20];

  float* ws = (float*)d_ws;
  const int NHW = N_*HW_, NC = N_*C_;
  float* mask_fg = ws;                 // [NHW]  direct store
  float* ctx_s   = ws + NHW;           // [NC]   direct store
  float* ctx_t   = ctx_s + NC;         // [NC]   direct store
  float* zbase   = ctx_t + NC;         // zeroed region starts here
  float* fea_s = zbase;                // [NHW] atomic
  float* fea_t = fea_s + NHW;          // [NHW] atomic
  float* cmp_s = fea_t + NHW;          // [NHW] atomic, later softmax p in-place
  float* cmp_t = cmp_s + NHW;          // [NHW]
  float* ch_s  = cmp_t + NHW;          // [NC]  atomic
  float* ch_t  = ch_s + NC;            // [NC]
  float* sum_d = ch_t + NC;            // [NC]
  float* acc   = sum_d + NC;           // [16]
  size_t zbytes = (size_t)(4*NHW + 3*NC + 16)*sizeof(float);
  hipMemsetAsync(zbase, 0, zbytes, stream);

  k_masks  <<<N_*PB_,     256, 0, stream>>>(gt, imh, imw, mask_fg, acc);
  k_pass1  <<<N_*PB_*CC_, 256, 0, stream>>>(S,T,cms_w,cmt_w,mask_fg,
                                            fea_s,fea_t,cmp_s,cmp_t,
                                            ch_s,ch_t,sum_d,acc);
  k_spatial<<<N_,         256, 0, stream>>>(fea_s,fea_t,cmp_s,cmp_t,acc);
  k_channel<<<N_,         256, 0, stream>>>(ch_s,ch_t,acc);
  k_pass2  <<<NC,         256, 0, stream>>>(S,T,cmp_s,cmp_t,ctx_s,ctx_t);
  k_cadd   <<<N_,         256, 0, stream>>>(ctx_s,ctx_t,
                                            cas_w1,cas_b1,cas_lnw,cas_lnb,cas_w2,cas_b2,
                                            cat_w1,cat_b1,cat_lnw,cat_lnb,cat_w2,cat_b2,
                                            sum_d,acc);
  k_final  <<<1,           64, 0, stream>>>(acc,(float*)d_out);
}

// Round 2
// 204.605 us; speedup vs baseline: 1.3395x; 1.3395x over previous
//
#include <hip/hip_runtime.h>

#define N_    8
#define C_    256
#define H_    100
#define W_    152
#define HW_   (H_*W_)          // 15200
#define NT_   20
#define TEMP_ 0.5f
#define LN_EPS_ 1e-5f
#define PB_   ((HW_+255)/256)  // 60 pixel-blocks of 256 (masks kernel)

// pass1 tiling: 4 pixels/thread (float4), 32-channel chunks
#define CHK_  32
#define NCH_  (C_/CHK_)        // 8
#define PPB_  1024             // pixels per block
#define PB4_  ((HW_+PPB_-1)/PPB_) // 15

__device__ __forceinline__ float wred_sum(float v){
#pragma unroll
  for(int o=32;o;o>>=1) v += __shfl_xor(v,o,64);
  return v;
}
__device__ __forceinline__ float wred_max(float v){
#pragma unroll
  for(int o=32;o;o>>=1) v = fmaxf(v,__shfl_xor(v,o,64));
  return v;
}
// block-wide sum to ALL threads; sm must hold >=16 floats
__device__ float block_sum(float v, float* sm){
  v = wred_sum(v);
  int nw = (int)(blockDim.x>>6);
  __syncthreads();
  if((threadIdx.x&63)==0) sm[threadIdx.x>>6]=v;
  __syncthreads();
  float r=0.f;
  for(int i=0;i<nw;i++) r+=sm[i];
  return r;
}
__device__ float block_max(float v, float* sm){
  v = wred_max(v);
  int nw = (int)(blockDim.x>>6);
  __syncthreads();
  if((threadIdx.x&63)==0) sm[threadIdx.x>>6]=v;
  __syncthreads();
  float r=-3.4e38f;
  for(int i=0;i<nw;i++) r=fmaxf(r,sm[i]);
  return r;
}

// acc layout: 0 fg, 1 bg, 2 total_d2, 3 maskS, 4 maskC, 5 rela, 6..13 bgcnt[n]
__global__ void k_masks(const float* __restrict__ gt, const int* __restrict__ imh,
                        const int* __restrict__ imw,
                        float* __restrict__ mask_fg, float* __restrict__ acc){
  __shared__ float sm[16];
  int b = blockIdx.x;
  int n = b / PB_;
  int pp = (b % PB_)*256 + threadIdx.x;
  float sw = (float)W_ / (float)imw[0];
  float sh = (float)H_ / (float)imh[0];
  float fg = 0.f;
  bool valid = pp < HW_;
  if (valid){
    float hh = (float)(pp / W_);
    float ww = (float)(pp % W_);
#pragma unroll
    for(int t=0;t<NT_;t++){
      const float* bx = gt + ((size_t)(n*NT_)+t)*4;
      float wmin = floorf(bx[0]*sw);
      float hmin = floorf(bx[1]*sh);
      float wmax = ceilf (bx[2]*sw);
      float hmax = ceilf (bx[3]*sh);
      float area = 1.f/((hmax+1.f-hmin)*(wmax+1.f-wmin));
      bool in = (hh>=hmin)&&(hh<=hmax)&&(ww>=wmin)&&(ww<=wmax);
      fg = fmaxf(fg, in?area:0.f);
    }
    mask_fg[n*HW_+pp] = fg;
  }
  float bgf = (valid && fg<=0.f) ? 1.f : 0.f;
  float s = block_sum(bgf, sm);
  if(threadIdx.x==0) atomicAdd(&acc[6+n], s);
}

// Pass 1: per-pixel sums only (no cross-lane ops in hot loop).
// fea_{s,t} = sum_c |x|; cmp_{s,t} = sum_c w_c*x; d2 per pixel for the 3 scalars.
__global__ void __launch_bounds__(256) k_pass1(
    const float* __restrict__ S, const float* __restrict__ T,
    const float* __restrict__ ws_w, const float* __restrict__ wt_w,
    const float* __restrict__ mask_fg,
    float* __restrict__ fea_s, float* __restrict__ fea_t,
    float* __restrict__ cmp_s, float* __restrict__ cmp_t,
    float* __restrict__ acc){
  __shared__ float lw_s[CHK_], lw_t[CHK_];
  __shared__ float sm[16];
  int b = blockIdx.x;
  int cc = b % NCH_;
  int pb = (b/NCH_) % PB4_;
  int n  = b/(NCH_*PB4_);
  int c0 = cc*CHK_;
  int tid = threadIdx.x;
  if(tid<CHK_){ lw_s[tid]=ws_w[c0+tid]; lw_t[tid]=wt_w[c0+tid]; }
  __syncthreads();
  int pp = pb*PPB_ + tid*4;
  bool valid = pp < HW_;   // HW_ % 4 == 0 so all 4 lanes' pixels valid together
  const float4* Sp = (const float4*)(S + (size_t)(n*C_+c0)*HW_ + pp);
  const float4* Tp = (const float4*)(T + (size_t)(n*C_+c0)*HW_ + pp);
  float fs[4]={0,0,0,0}, ft[4]={0,0,0,0};
  float cs[4]={0,0,0,0}, ct[4]={0,0,0,0};
  float d2[4]={0,0,0,0};
  if(valid){
    for(int ci=0;ci<CHK_;ci++){
      float4 s4 = Sp[(size_t)ci*(HW_/4)];
      float4 t4 = Tp[(size_t)ci*(HW_/4)];
      float wsv = lw_s[ci], wtv = lw_t[ci];
      float se[4]={s4.x,s4.y,s4.z,s4.w};
      float te[4]={t4.x,t4.y,t4.z,t4.w};
#pragma unroll
      for(int k=0;k<4;k++){
        float sv=se[k], tv=te[k];
        fs[k] += fabsf(sv); ft[k] += fabsf(tv);
        cs[k] += wsv*sv;    ct[k] += wtv*tv;
        float d = sv-tv;    d2[k] += d*d;
      }
    }
#pragma unroll
    for(int k=0;k<4;k++){
      atomicAdd(&fea_s[n*HW_+pp+k], fs[k]);
      atomicAdd(&fea_t[n*HW_+pp+k], ft[k]);
      atomicAdd(&cmp_s[n*HW_+pp+k], cs[k]);
      atomicAdd(&cmp_t[n*HW_+pp+k], ct[k]);
    }
  }
  float wfg=0.f, wbg=0.f, wd2=0.f;
  if(valid){
    float4 m4 = *(const float4*)(mask_fg + n*HW_ + pp);
    float me[4]={m4.x,m4.y,m4.z,m4.w};
    float bgc = acc[6+n];
    float ibg = (bgc>0.f)?(1.f/bgc):1.f;
#pragma unroll
    for(int k=0;k<4;k++){
      float mfg = me[k];
      float mbg = (mfg<=0.f)? ibg : 0.f;
      wfg += mfg*mfg*d2[k];
      wbg += mbg*mbg*d2[k];
      wd2 += d2[k];
    }
  }
  float s1 = block_sum(wfg, sm); if(tid==0) atomicAdd(&acc[0], s1);
  float s2 = block_sum(wbg, sm); if(tid==0) atomicAdd(&acc[1], s2);
  float s3 = block_sum(wd2, sm); if(tid==0) atomicAdd(&acc[2], s3);
}

__global__ void k_spatial(const float* __restrict__ fea_s, const float* __restrict__ fea_t,
                          float* __restrict__ cmp_s, float* __restrict__ cmp_t,
                          float* __restrict__ acc){
  __shared__ float sm[16];
  int n = blockIdx.x, tid = threadIdx.x;
  int nt = blockDim.x;
  const float* fs = fea_s + n*HW_;
  const float* ft = fea_t + n*HW_;
  float* cs = cmp_s + n*HW_;
  float* ct = cmp_t + n*HW_;
  const float invf = 1.f/((float)C_*TEMP_);
  float m1=-3.4e38f,m2=-3.4e38f,m3=-3.4e38f,m4=-3.4e38f;
  for(int p=tid;p<HW_;p+=nt){
    m1=fmaxf(m1,fs[p]); m2=fmaxf(m2,ft[p]);
    m3=fmaxf(m3,cs[p]); m4=fmaxf(m4,ct[p]);
  }
  m1=block_max(m1,sm); m2=block_max(m2,sm);
  m3=block_max(m3,sm); m4=block_max(m4,sm);
  float z1=0,z2=0,z3=0,z4=0;
  for(int p=tid;p<HW_;p+=nt){
    z1+=expf((fs[p]-m1)*invf); z2+=expf((ft[p]-m2)*invf);
    z3+=expf(cs[p]-m3);        z4+=expf(ct[p]-m4);
  }
  z1=block_sum(z1,sm); z2=block_sum(z2,sm);
  z3=block_sum(z3,sm); z4=block_sum(z4,sm);
  float i1=(float)HW_/z1, i2=(float)HW_/z2, i3=1.f/z3, i4=1.f/z4;
  float dacc=0.f;
  for(int p=tid;p<HW_;p+=nt){
    float Ss = expf((fs[p]-m1)*invf)*i1;
    float St = expf((ft[p]-m2)*invf)*i2;
    dacc += fabsf(Ss-St);
    float ps = expf(cs[p]-m3)*i3;
    float pt = expf(ct[p]-m4)*i4;
    cs[p]=ps; ct[p]=pt;
  }
  dacc = block_sum(dacc,sm);
  if(tid==0) atomicAdd(&acc[3], dacc);
}

// Pass 2: block per (n,c). ctx dot products + the linear channel sums
// (sum|s|, sum|t|, sum(s-t)) folded in (3 extra VALU/elem, reductions amortized).
__global__ void __launch_bounds__(256) k_pass2(
    const float* __restrict__ S, const float* __restrict__ T,
    const float* __restrict__ cmp_s, const float* __restrict__ cmp_t,
    float* __restrict__ ctx_s, float* __restrict__ ctx_t,
    float* __restrict__ ch_s, float* __restrict__ ch_t,
    float* __restrict__ sum_d){
  __shared__ float sm[16];
  int b=blockIdx.x;
  int n=b>>8, c=b&255;
  const float4* Sp = (const float4*)(S + (size_t)(n*C_+c)*HW_);
  const float4* Tp = (const float4*)(T + (size_t)(n*C_+c)*HW_);
  const float4* Pp = (const float4*)(cmp_s + n*HW_);
  const float4* Qp = (const float4*)(cmp_t + n*HW_);
  float as=0.f, at=0.f, dd=0.f, xs=0.f, xt=0.f;
  for(int p=threadIdx.x;p<HW_/4;p+=256){
    float4 s=Sp[p], t=Tp[p], u=Pp[p], v=Qp[p];
    as += fabsf(s.x)+fabsf(s.y)+fabsf(s.z)+fabsf(s.w);
    at += fabsf(t.x)+fabsf(t.y)+fabsf(t.z)+fabsf(t.w);
    dd += (s.x-t.x)+(s.y-t.y)+(s.z-t.z)+(s.w-t.w);
    xs += s.x*u.x+s.y*u.y+s.z*u.z+s.w*u.w;
    xt += t.x*v.x+t.y*v.y+t.z*v.z+t.w*v.w;
  }
  as = block_sum(as,sm);
  at = block_sum(at,sm);
  dd = block_sum(dd,sm);
  xs = block_sum(xs,sm);
  xt = block_sum(xt,sm);
  if(threadIdx.x==0){
    ch_s[n*C_+c]=as; ch_t[n*C_+c]=at; sum_d[n*C_+c]=dd;
    ctx_s[n*C_+c]=xs; ctx_t[n*C_+c]=xt;
  }
}

__global__ void k_channel(const float* __restrict__ ch_s, const float* __restrict__ ch_t,
                          float* __restrict__ acc){
  __shared__ float sm[16];
  int n=blockIdx.x, c=threadIdx.x;
  const float invc = 1.f/((float)HW_*TEMP_);
  float vs = ch_s[n*C_+c]*invc;
  float vt = ch_t[n*C_+c]*invc;
  float ms = block_max(vs,sm);
  float mt = block_max(vt,sm);
  float es = expf(vs-ms), et = expf(vt-mt);
  float zs = block_sum(es,sm), zt = block_sum(et,sm);
  float Cs = (float)C_*es/zs, Ct = (float)C_*et/zt;
  float d = block_sum(fabsf(Cs-Ct), sm);
  if(c==0) atomicAdd(&acc[4], d);
}

__global__ void k_cadd(const float* __restrict__ ctx_s, const float* __restrict__ ctx_t,
    const float* __restrict__ sw1, const float* __restrict__ sb1,
    const float* __restrict__ slnw, const float* __restrict__ slnb,
    const float* __restrict__ sw2, const float* __restrict__ sb2,
    const float* __restrict__ tw1, const float* __restrict__ tb1,
    const float* __restrict__ tlnw, const float* __restrict__ tlnb,
    const float* __restrict__ tw2, const float* __restrict__ tb2,
    const float* __restrict__ sum_d, float* __restrict__ acc){
  __shared__ float sm[16];
  __shared__ float lcs[C_], lct[C_], ly[C_], lh[C_];
  int n=blockIdx.x, tid=threadIdx.x;
  lcs[tid]=ctx_s[n*C_+tid]; lct[tid]=ctx_t[n*C_+tid];
  __syncthreads();
  {
    int half = tid>>7, k = tid&127;
    const float* w1  = half? tw1 : sw1;
    const float* b1  = half? tb1 : sb1;
    const float* src = half? lct : lcs;
    float a = b1[k];
    for(int c=0;c<C_;c++) a += src[c]*w1[k*C_+c];
    ly[tid]=a;
  }
  __syncthreads();
  {
    int half = tid>>7, k = tid&127;
    int base = half<<7;
    float mu=0.f;
    for(int i=0;i<128;i++) mu += ly[base+i];
    mu *= (1.f/128.f);
    float var=0.f;
    for(int i=0;i<128;i++){ float d=ly[base+i]-mu; var += d*d; }
    var *= (1.f/128.f);
    const float* lnw = half? tlnw : slnw;
    const float* lnb = half? tlnb : slnb;
    float yv = (ly[tid]-mu)/sqrtf(var+LN_EPS_)*lnw[k]+lnb[k];
    lh[tid] = fmaxf(yv, 0.f);
  }
  __syncthreads();
  {
    int c = tid;
    float os = sb2[c], ot = tb2[c];
    for(int k=0;k<128;k++){ os += lh[k]*sw2[c*128+k]; ot += lh[128+k]*tw2[c*128+k]; }
    float e = os - ot;
    float part = 2.f*e*sum_d[n*C_+c] + (float)HW_*e*e;
    float s = block_sum(part, sm);
    if(tid==0) atomicAdd(&acc[5], s);
  }
}

__global__ void k_final(const float* __restrict__ acc, float* __restrict__ out){
  if(threadIdx.x==0 && blockIdx.x==0){
    float fg=acc[0], bg=acc[1], d2=acc[2], mS=acc[3], mC=acc[4], rl=acc[5];
    const float invN = 1.f/(float)N_;
    out[0] = 0.001f*fg*invN + 0.0005f*bg*invN
           + 0.001f*(mC+mS)*invN + 5e-6f*(d2+rl)*invN;
  }
}

extern "C" void kernel_launch(void* const* d_in, const int* in_sizes, int n_in,
                              void* d_out, int out_size, void* d_ws, size_t ws_size,
                              hipStream_t stream){
  (void)in_sizes; (void)n_in; (void)out_size; (void)ws_size;
  const float* S     = (const float*)d_in[0];
  const float* T     = (const float*)d_in[1];
  const float* gt    = (const float*)d_in[2];
  const float* cms_w = (const float*)d_in[3];
  const float* cmt_w = (const float*)d_in[5];
  const float* cas_w1=(const float*)d_in[7],  *cas_b1=(const float*)d_in[8];
  const float* cas_lnw=(const float*)d_in[9], *cas_lnb=(const float*)d_in[10];
  const float* cas_w2=(const float*)d_in[11], *cas_b2=(const float*)d_in[12];
  const float* cat_w1=(const float*)d_in[13], *cat_b1=(const float*)d_in[14];
  const float* cat_lnw=(const float*)d_in[15],*cat_lnb=(const float*)d_in[16];
  const float* cat_w2=(const float*)d_in[17], *cat_b2=(const float*)d_in[18];
  const int* imh=(const int*)d_in[19];
  const int* imw=(const int*)d_in[20];

  float* ws = (float*)d_ws;
  const int NHW = N_*HW_, NC = N_*C_;
  float* mask_fg = ws;                 // [NHW]  direct store
  float* ctx_s   = ws + NHW;           // [NC]   direct store (pass2)
  float* ctx_t   = ctx_s + NC;         // [NC]
  float* ch_s    = ctx_t + NC;         // [NC]   direct store (pass2)
  float* ch_t    = ch_s + NC;          // [NC]
  float* sum_d   = ch_t + NC;          // [NC]
  float* zbase   = sum_d + NC;         // zeroed region starts here
  float* fea_s = zbase;                // [NHW] atomic
  float* fea_t = fea_s + NHW;          // [NHW] atomic
  float* cmp_s = fea_t + NHW;          // [NHW] atomic, later softmax p in-place
  float* cmp_t = cmp_s + NHW;          // [NHW]
  float* acc   = cmp_t + NHW;          // [16]
  size_t zbytes = (size_t)(4*NHW + 16)*sizeof(float);
  hipMemsetAsync(zbase, 0, zbytes, stream);

  k_masks  <<<N_*PB_,        256, 0, stream>>>(gt, imh, imw, mask_fg, acc);
  k_pass1  <<<N_*PB4_*NCH_,  256, 0, stream>>>(S,T,cms_w,cmt_w,mask_fg,
                                               fea_s,fea_t,cmp_s,cmp_t,acc);
  k_spatial<<<N_,           1024, 0, stream>>>(fea_s,fea_t,cmp_s,cmp_t,acc);
  k_pass2  <<<N_*C_,         256, 0, stream>>>(S,T,cmp_s,cmp_t,
                                               ctx_s,ctx_t,ch_s,ch_t,sum_d);
  k_channel<<<N_,            256, 0, stream>>>(ch_s,ch_t,acc);
  k_cadd   <<<N_,            256, 0, stream>>>(ctx_s,ctx_t,
                                               cas_w1,cas_b1,cas_lnw,cas_lnb,cas_w2,cas_b2,
                                               cat_w1,cat_b1,cat_lnw,cat_lnb,cat_w2,cat_b2,
                                               sum_d,acc);
  k_final  <<<1,              64, 0, stream>>>(acc,(float*)d_out);
}

// Round 3
// 175.081 us; speedup vs baseline: 1.5653x; 1.1686x over previous
//
#include <hip/hip_runtime.h>

#define N_    8
#define C_    256
#define H_    100
#define W_    152
#define HW_   (H_*W_)          // 15200
#define NT_   20
#define TEMP_ 0.5f
#define LN_EPS_ 1e-5f
#define PB_   ((HW_+255)/256)  // 60 pixel-blocks of 256

__device__ __forceinline__ float wred_sum(float v){
#pragma unroll
  for(int o=32;o;o>>=1) v += __shfl_xor(v,o,64);
  return v;
}
__device__ __forceinline__ float wred_max(float v){
#pragma unroll
  for(int o=32;o;o>>=1) v = fmaxf(v,__shfl_xor(v,o,64));
  return v;
}
__device__ float block_sum(float v, float* sm){
  v = wred_sum(v);
  int nw = (int)(blockDim.x>>6);
  __syncthreads();
  if((threadIdx.x&63)==0) sm[threadIdx.x>>6]=v;
  __syncthreads();
  float r=0.f;
  for(int i=0;i<nw;i++) r+=sm[i];
  return r;
}
__device__ float block_max(float v, float* sm){
  v = wred_max(v);
  int nw = (int)(blockDim.x>>6);
  __syncthreads();
  if((threadIdx.x&63)==0) sm[threadIdx.x>>6]=v;
  __syncthreads();
  float r=-3.4e38f;
  for(int i=0;i<nw;i++) r=fmaxf(r,sm[i]);
  return r;
}

// acc: 0 fg, 1 bg, 2 total_d2, 3 maskS, 4 maskC, 5 rela, 6..13 bgcnt[n]
__global__ void k_masks(const float* __restrict__ gt, const int* __restrict__ imh,
                        const int* __restrict__ imw,
                        float* __restrict__ mask_fg, float* __restrict__ acc){
  __shared__ float sm[16];
  int b = blockIdx.x;
  int n = b / PB_;
  int pp = (b % PB_)*256 + threadIdx.x;
  float sw = (float)W_ / (float)imw[0];
  float sh = (float)H_ / (float)imh[0];
  float fg = 0.f;
  bool valid = pp < HW_;
  if (valid){
    float hh = (float)(pp / W_);
    float ww = (float)(pp % W_);
#pragma unroll
    for(int t=0;t<NT_;t++){
      const float* bx = gt + ((size_t)(n*NT_)+t)*4;
      float wmin = floorf(bx[0]*sw);
      float hmin = floorf(bx[1]*sh);
      float wmax = ceilf (bx[2]*sw);
      float hmax = ceilf (bx[3]*sh);
      float area = 1.f/((hmax+1.f-hmin)*(wmax+1.f-wmin));
      bool in = (hh>=hmin)&&(hh<=hmax)&&(ww>=wmin)&&(ww<=wmax);
      fg = fmaxf(fg, in?area:0.f);
    }
    mask_fg[n*HW_+pp] = fg;
  }
  float bgf = (valid && fg<=0.f) ? 1.f : 0.f;
  float s = block_sum(bgf, sm);
  if(threadIdx.x==0) atomicAdd(&acc[6+n], s);
}

// Pass 1: block = (n, 256-pixel chunk), ALL 256 channels (64 per wave).
// Per-pixel sums combined across waves in LDS; single coalesced store.
// No global atomics except 3 scalars into acc.
__global__ void __launch_bounds__(256) k_pass1(
    const float* __restrict__ S, const float* __restrict__ T,
    const float* __restrict__ ws_w, const float* __restrict__ wt_w,
    const float* __restrict__ mask_fg,
    float* __restrict__ fea_s, float* __restrict__ fea_t,
    float* __restrict__ cmp_s, float* __restrict__ cmp_t,
    float* __restrict__ acc){
  __shared__ float lw_s[C_], lw_t[C_];
  __shared__ float4 comb[4][4][64];   // [wave][quantity][px4] = 16 KB
  __shared__ float sm[16];
  int b = blockIdx.x;
  int n = b / PB_, pb = b % PB_;
  int tid = threadIdx.x, wv = tid>>6, ln = tid&63;
  lw_s[tid] = ws_w[tid];
  lw_t[tid] = wt_w[tid];
  __syncthreads();
  int px = pb*256 + ln*4;
  bool valid = px < HW_;              // HW_%4==0 -> whole float4 valid together
  int c0 = wv*64;
  float fs[4]={0,0,0,0}, ft[4]={0,0,0,0};
  float cs[4]={0,0,0,0}, ct[4]={0,0,0,0};
  float d2[4]={0,0,0,0};
  if(valid){
    const float4* Sp = (const float4*)(S + (size_t)(n*C_+c0)*HW_ + px);
    const float4* Tp = (const float4*)(T + (size_t)(n*C_+c0)*HW_ + px);
#pragma unroll 4
    for(int ci=0;ci<64;ci++){
      float4 s4 = Sp[(size_t)ci*(HW_/4)];
      float4 t4 = Tp[(size_t)ci*(HW_/4)];
      float wsv = lw_s[c0+ci], wtv = lw_t[c0+ci];
      float se[4]={s4.x,s4.y,s4.z,s4.w};
      float te[4]={t4.x,t4.y,t4.z,t4.w};
#pragma unroll
      for(int k=0;k<4;k++){
        float sv=se[k], tv=te[k];
        fs[k] += fabsf(sv); ft[k] += fabsf(tv);
        cs[k] += wsv*sv;    ct[k] += wtv*tv;
        float d = sv-tv;    d2[k] += d*d;
      }
    }
  }
  comb[wv][0][ln] = make_float4(fs[0],fs[1],fs[2],fs[3]);
  comb[wv][1][ln] = make_float4(ft[0],ft[1],ft[2],ft[3]);
  comb[wv][2][ln] = make_float4(cs[0],cs[1],cs[2],cs[3]);
  comb[wv][3][ln] = make_float4(ct[0],ct[1],ct[2],ct[3]);
  __syncthreads();
  {
    int q = tid>>6, i = tid&63;
    int opx = pb*256 + i*4;
    if(opx < HW_){
      float4 a=comb[0][q][i], b4=comb[1][q][i], c4=comb[2][q][i], e4=comb[3][q][i];
      float4 r = make_float4(a.x+b4.x+c4.x+e4.x, a.y+b4.y+c4.y+e4.y,
                             a.z+b4.z+c4.z+e4.z, a.w+b4.w+c4.w+e4.w);
      float* dst = (q==0)?fea_s : (q==1)?fea_t : (q==2)?cmp_s : cmp_t;
      *(float4*)(dst + n*HW_ + opx) = r;
    }
  }
  float wfg=0.f, wbg=0.f, wd2=0.f;
  if(valid){
    float4 m4 = *(const float4*)(mask_fg + n*HW_ + px);
    float me[4]={m4.x,m4.y,m4.z,m4.w};
    float bgc = acc[6+n];
    float ibg = (bgc>0.f)?(1.f/bgc):1.f;
#pragma unroll
    for(int k=0;k<4;k++){
      float mfg = me[k];
      float mbg = (mfg<=0.f)? ibg : 0.f;
      wfg += mfg*mfg*d2[k];
      wbg += mbg*mbg*d2[k];
      wd2 += d2[k];
    }
  }
  float s1 = block_sum(wfg, sm); if(tid==0) atomicAdd(&acc[0], s1);
  float s2 = block_sum(wbg, sm); if(tid==0) atomicAdd(&acc[1], s2);
  float s3 = block_sum(wd2, sm); if(tid==0) atomicAdd(&acc[2], s3);
}

__global__ void k_spatial(const float* __restrict__ fea_s, const float* __restrict__ fea_t,
                          float* __restrict__ cmp_s, float* __restrict__ cmp_t,
                          float* __restrict__ acc){
  __shared__ float sm[16];
  int n = blockIdx.x, tid = threadIdx.x;
  int nt = blockDim.x;
  const float* fs = fea_s + n*HW_;
  const float* ft = fea_t + n*HW_;
  float* cs = cmp_s + n*HW_;
  float* ct = cmp_t + n*HW_;
  const float invf = 1.f/((float)C_*TEMP_);
  float m1=-3.4e38f,m2=-3.4e38f,m3=-3.4e38f,m4=-3.4e38f;
  for(int p=tid;p<HW_;p+=nt){
    m1=fmaxf(m1,fs[p]); m2=fmaxf(m2,ft[p]);
    m3=fmaxf(m3,cs[p]); m4=fmaxf(m4,ct[p]);
  }
  m1=block_max(m1,sm); m2=block_max(m2,sm);
  m3=block_max(m3,sm); m4=block_max(m4,sm);
  float z1=0,z2=0,z3=0,z4=0;
  for(int p=tid;p<HW_;p+=nt){
    z1+=expf((fs[p]-m1)*invf); z2+=expf((ft[p]-m2)*invf);
    z3+=expf(cs[p]-m3);        z4+=expf(ct[p]-m4);
  }
  z1=block_sum(z1,sm); z2=block_sum(z2,sm);
  z3=block_sum(z3,sm); z4=block_sum(z4,sm);
  float i1=(float)HW_/z1, i2=(float)HW_/z2, i3=1.f/z3, i4=1.f/z4;
  float dacc=0.f;
  for(int p=tid;p<HW_;p+=nt){
    float Ss = expf((fs[p]-m1)*invf)*i1;
    float St = expf((ft[p]-m2)*invf)*i2;
    dacc += fabsf(Ss-St);
    float ps = expf(cs[p]-m3)*i3;
    float pt = expf(ct[p]-m4)*i4;
    cs[p]=ps; ct[p]=pt;
  }
  dacc = block_sum(dacc,sm);
  if(tid==0) atomicAdd(&acc[3], dacc);
}

// Pass 2: block per (n,c): ctx dots + linear channel sums.
__global__ void __launch_bounds__(256) k_pass2(
    const float* __restrict__ S, const float* __restrict__ T,
    const float* __restrict__ cmp_s, const float* __restrict__ cmp_t,
    float* __restrict__ ctx_s, float* __restrict__ ctx_t,
    float* __restrict__ ch_s, float* __restrict__ ch_t,
    float* __restrict__ sum_d){
  __shared__ float sm[16];
  int b=blockIdx.x;
  int n=b>>8, c=b&255;
  const float4* Sp = (const float4*)(S + (size_t)(n*C_+c)*HW_);
  const float4* Tp = (const float4*)(T + (size_t)(n*C_+c)*HW_);
  const float4* Pp = (const float4*)(cmp_s + n*HW_);
  const float4* Qp = (const float4*)(cmp_t + n*HW_);
  float as=0.f, at=0.f, dd=0.f, xs=0.f, xt=0.f;
  for(int p=threadIdx.x;p<HW_/4;p+=256){
    float4 s=Sp[p], t=Tp[p], u=Pp[p], v=Qp[p];
    as += fabsf(s.x)+fabsf(s.y)+fabsf(s.z)+fabsf(s.w);
    at += fabsf(t.x)+fabsf(t.y)+fabsf(t.z)+fabsf(t.w);
    dd += (s.x-t.x)+(s.y-t.y)+(s.z-t.z)+(s.w-t.w);
    xs += s.x*u.x+s.y*u.y+s.z*u.z+s.w*u.w;
    xt += t.x*v.x+t.y*v.y+t.z*v.z+t.w*v.w;
  }
  as = block_sum(as,sm);
  at = block_sum(at,sm);
  dd = block_sum(dd,sm);
  xs = block_sum(xs,sm);
  xt = block_sum(xt,sm);
  if(threadIdx.x==0){
    ch_s[n*C_+c]=as; ch_t[n*C_+c]=at; sum_d[n*C_+c]=dd;
    ctx_s[n*C_+c]=xs; ctx_t[n*C_+c]=xt;
  }
}

__global__ void k_channel(const float* __restrict__ ch_s, const float* __restrict__ ch_t,
                          float* __restrict__ acc){
  __shared__ float sm[16];
  int n=blockIdx.x, c=threadIdx.x;
  const float invc = 1.f/((float)HW_*TEMP_);
  float vs = ch_s[n*C_+c]*invc;
  float vt = ch_t[n*C_+c]*invc;
  float ms = block_max(vs,sm);
  float mt = block_max(vt,sm);
  float es = expf(vs-ms), et = expf(vt-mt);
  float zs = block_sum(es,sm), zt = block_sum(et,sm);
  float Cs = (float)C_*es/zs, Ct = (float)C_*et/zt;
  float d = block_sum(fabsf(Cs-Ct), sm);
  if(c==0) atomicAdd(&acc[4], d);
}

// Transpose the 4 small weight matrices into ws so k_cadd reads coalesced.
// out layout: [w1T_s | w1T_t | w2T_s | w2T_t], each 128*256 floats.
// w1 (128x256) -> w1T[c*128+k]; w2 (256x128) -> w2T[k*256+c].
__global__ void k_tw(const float* __restrict__ sw1, const float* __restrict__ tw1,
                     const float* __restrict__ sw2, const float* __restrict__ tw2,
                     float* __restrict__ o){
  int g = blockIdx.x;
  int which = g>>7;
  int i = (g&127)*256 + threadIdx.x;
  const float* src = (which==0)?sw1 : (which==1)?tw1 : (which==2)?sw2 : tw2;
  int Ccols = (which<2)?256:128;
  int Rrows = (which<2)?128:256;
  int r = i/Ccols, c = i%Ccols;
  o[which*32768 + c*Rrows + r] = src[i];
}

__global__ void k_cadd(const float* __restrict__ ctx_s, const float* __restrict__ ctx_t,
    const float* __restrict__ wT,
    const float* __restrict__ sb1, const float* __restrict__ slnw, const float* __restrict__ slnb,
    const float* __restrict__ sb2,
    const float* __restrict__ tb1, const float* __restrict__ tlnw, const float* __restrict__ tlnb,
    const float* __restrict__ tb2,
    const float* __restrict__ sum_d, float* __restrict__ acc){
  __shared__ float sm[16];
  __shared__ float sred[8];
  __shared__ float lcs[C_], lct[C_], lh[C_];
  const float* w1T_s = wT;
  const float* w1T_t = wT + 32768;
  const float* w2T_s = wT + 65536;
  const float* w2T_t = wT + 98304;
  int n=blockIdx.x, tid=threadIdx.x;
  lcs[tid]=ctx_s[n*C_+tid]; lct[tid]=ctx_t[n*C_+tid];
  __syncthreads();
  int half = tid>>7, k = tid&127;
  float y;
  {
    const float* w1T = half? w1T_t : w1T_s;
    const float* b1  = half? tb1 : sb1;
    const float* src = half? lct : lcs;
    float a = b1[k];
    for(int c=0;c<C_;c++) a += src[c]*w1T[c*128+k];
    y = a;
  }
  // LayerNorm over each 128-half via wave reductions
  {
    int wv = tid>>6;
    float s1 = wred_sum(y);
    float s2 = wred_sum(y*y);
    __syncthreads();
    if((tid&63)==0){ sred[wv]=s1; sred[4+wv]=s2; }
    __syncthreads();
    int h2 = half<<1;
    float mu = (sred[h2]+sred[h2+1])*(1.f/128.f);
    float ms = (sred[4+h2]+sred[4+h2+1])*(1.f/128.f);
    float var = ms - mu*mu;
    const float* lnw = half? tlnw : slnw;
    const float* lnb = half? tlnb : slnb;
    float yv = (y-mu)/sqrtf(var+LN_EPS_)*lnw[k]+lnb[k];
    lh[tid] = fmaxf(yv, 0.f);
  }
  __syncthreads();
  {
    int c = tid;
    float os = sb2[c], ot = tb2[c];
    for(int kk=0;kk<128;kk++){
      os += lh[kk]*w2T_s[kk*256+c];
      ot += lh[128+kk]*w2T_t[kk*256+c];
    }
    float e = os - ot;
    float part = 2.f*e*sum_d[n*C_+c] + (float)HW_*e*e;
    float s = block_sum(part, sm);
    if(tid==0) atomicAdd(&acc[5], s);
  }
}

__global__ void k_final(const float* __restrict__ acc, float* __restrict__ out){
  if(threadIdx.x==0 && blockIdx.x==0){
    float fg=acc[0], bg=acc[1], d2=acc[2], mS=acc[3], mC=acc[4], rl=acc[5];
    const float invN = 1.f/(float)N_;
    out[0] = 0.001f*fg*invN + 0.0005f*bg*invN
           + 0.001f*(mC+mS)*invN + 5e-6f*(d2+rl)*invN;
  }
}

extern "C" void kernel_launch(void* const* d_in, const int* in_sizes, int n_in,
                              void* d_out, int out_size, void* d_ws, size_t ws_size,
                              hipStream_t stream){
  (void)in_sizes; (void)n_in; (void)out_size; (void)ws_size;
  const float* S     = (const float*)d_in[0];
  const float* T     = (const float*)d_in[1];
  const float* gt    = (const float*)d_in[2];
  const float* cms_w = (const float*)d_in[3];
  const float* cmt_w = (const float*)d_in[5];
  const float* cas_w1=(const float*)d_in[7],  *cas_b1=(const float*)d_in[8];
  const float* cas_lnw=(const float*)d_in[9], *cas_lnb=(const float*)d_in[10];
  const float* cas_w2=(const float*)d_in[11], *cas_b2=(const float*)d_in[12];
  const float* cat_w1=(const float*)d_in[13], *cat_b1=(const float*)d_in[14];
  const float* cat_lnw=(const float*)d_in[15],*cat_lnb=(const float*)d_in[16];
  const float* cat_w2=(const float*)d_in[17], *cat_b2=(const float*)d_in[18];
  const int* imh=(const int*)d_in[19];
  const int* imw=(const int*)d_in[20];

  float* ws = (float*)d_ws;
  const int NHW = N_*HW_, NC = N_*C_;
  float* mask_fg = ws;                 // [NHW]
  float* fea_s = mask_fg + NHW;        // [NHW] direct store
  float* fea_t = fea_s + NHW;          // [NHW]
  float* cmp_s = fea_t + NHW;          // [NHW] later softmax p in place
  float* cmp_t = cmp_s + NHW;          // [NHW]
  float* ctx_s = cmp_t + NHW;          // [NC]
  float* ctx_t = ctx_s + NC;
  float* ch_s  = ctx_t + NC;
  float* ch_t  = ch_s + NC;
  float* sum_d = ch_t + NC;
  float* wT    = sum_d + NC;           // [4*32768]
  float* acc   = wT + 4*32768;         // [16] zeroed
  hipMemsetAsync(acc, 0, 16*sizeof(float), stream);

  k_tw     <<<512,        256, 0, stream>>>(cas_w1,cat_w1,cas_w2,cat_w2, wT);
  k_masks  <<<N_*PB_,     256, 0, stream>>>(gt, imh, imw, mask_fg, acc);
  k_pass1  <<<N_*PB_,     256, 0, stream>>>(S,T,cms_w,cmt_w,mask_fg,
                                            fea_s,fea_t,cmp_s,cmp_t,acc);
  k_spatial<<<N_,        1024, 0, stream>>>(fea_s,fea_t,cmp_s,cmp_t,acc);
  k_pass2  <<<N_*C_,      256, 0, stream>>>(S,T,cmp_s,cmp_t,
                                            ctx_s,ctx_t,ch_s,ch_t,sum_d);
  k_channel<<<N_,         256, 0, stream>>>(ch_s,ch_t,acc);
  k_cadd   <<<N_,         256, 0, stream>>>(ctx_s,ctx_t, wT,
                                            cas_b1,cas_lnw,cas_lnb,cas_b2,
                                            cat_b1,cat_lnw,cat_lnb,cat_b2,
                                            sum_d,acc);
  k_final  <<<1,           64, 0, stream>>>(acc,(float*)d_out);
}